// Round 1
// baseline (14764.001 us; speedup 1.0000x reference)
//
#include <hip/hip_runtime.h>
#include <hip/hip_bf16.h>
#include <stdint.h>

#define TT 2048
#define DD 2048
#define HDIM 1024
#define G4 4096
#define KTAG 22
#define END_TAG 20
#define START_TAG 21
#define NEGV (-10000.0f)

typedef __attribute__((ext_vector_type(8))) short bf16x8;
typedef __attribute__((ext_vector_type(4))) float f32x4;

__device__ __forceinline__ float sigm(float x) { return 1.0f / (1.0f + __expf(-x)); }
__device__ __forceinline__ float tanh_fast(float x) {
    float e = __expf(2.0f * x);
    return 1.0f - 2.0f / (e + 1.0f);
}

// ---------------- prep: fp32 -> bf16 ----------------
__global__ void convert_bf16_k(const float* __restrict__ src, __hip_bfloat16* __restrict__ dst, int n) {
    int i = blockIdx.x * blockDim.x + threadIdx.x;
    int stride = gridDim.x * blockDim.x;
    for (; i < n; i += stride) dst[i] = __float2bfloat16(src[i]);
}

__global__ void make_bias_k(const float* __restrict__ bih_f, const float* __restrict__ bhh_f,
                            const float* __restrict__ bih_r, const float* __restrict__ bhh_r,
                            float* __restrict__ ball) {
    int j = blockIdx.x * 256 + threadIdx.x;
    if (j < G4) ball[j] = bih_f[j] + bhh_f[j];
    else if (j < 2 * G4) ball[j] = bih_r[j - G4] + bhh_r[j - G4];
}

// ---------------- GEMM: X[t][j] = sum_k seq[t][k]*W[j][k] + bias[j] ----------------
// A: [2048][2048] bf16 row-major (K contig); B: [8192][2048] bf16 row-major (K contig)
// X: [2048][8192] fp32
#define LDT 40
__global__ __launch_bounds__(256) void gemm_x_k(const __hip_bfloat16* __restrict__ A,
                                                const __hip_bfloat16* __restrict__ B,
                                                const float* __restrict__ bias,
                                                float* __restrict__ X) {
    __shared__ unsigned short As[128 * LDT];
    __shared__ unsigned short Bs[128 * LDT];
    const int tid  = threadIdx.x;
    const int lane = tid & 63;
    const int wave = tid >> 6;
    const int wm = wave >> 1, wn = wave & 1;
    const int m0 = blockIdx.y * 128, n0 = blockIdx.x * 128;
    const int r15 = lane & 15, quad = lane >> 4;

    f32x4 acc[4][4];
#pragma unroll
    for (int i = 0; i < 4; ++i)
#pragma unroll
        for (int j = 0; j < 4; ++j) acc[i][j] = (f32x4){0.f, 0.f, 0.f, 0.f};

    for (int kt = 0; kt < DD; kt += 32) {
#pragma unroll
        for (int it = 0; it < 2; ++it) {
            int idx = it * 256 + tid;
            int row = idx >> 2, ch = idx & 3;
            uint4 va = *(const uint4*)(A + (size_t)(m0 + row) * DD + kt + ch * 8);
            *(uint4*)(&As[row * LDT + ch * 8]) = va;
            uint4 vb = *(const uint4*)(B + (size_t)(n0 + row) * DD + kt + ch * 8);
            *(uint4*)(&Bs[row * LDT + ch * 8]) = vb;
        }
        __syncthreads();
        bf16x8 af[4], bfr[4];
#pragma unroll
        for (int i = 0; i < 4; ++i)
            af[i] = *(const bf16x8*)(&As[(wm * 64 + i * 16 + r15) * LDT + quad * 8]);
#pragma unroll
        for (int j = 0; j < 4; ++j)
            bfr[j] = *(const bf16x8*)(&Bs[(wn * 64 + j * 16 + r15) * LDT + quad * 8]);
#pragma unroll
        for (int i = 0; i < 4; ++i)
#pragma unroll
            for (int j = 0; j < 4; ++j)
                acc[i][j] = __builtin_amdgcn_mfma_f32_16x16x32_bf16(af[i], bfr[j], acc[i][j], 0, 0, 0);
        __syncthreads();
    }
#pragma unroll
    for (int i = 0; i < 4; ++i) {
#pragma unroll
        for (int j = 0; j < 4; ++j) {
            int col = n0 + wn * 64 + j * 16 + r15;
            float b = bias[col];
#pragma unroll
            for (int r = 0; r < 4; ++r) {
                int row = m0 + wm * 64 + i * 16 + quad * 4 + r;
                X[(size_t)row * (2 * G4) + col] = acc[i][j][r] + b;
            }
        }
    }
}

// ---------------- persistent bidirectional LSTM recurrence ----------------
// grid = 128 WGs: dir = bid&1, slice = bid>>1 (64 slices/dir). 512 threads (8 waves).
// Each lane owns Whh[row][c0..c0+128) in VGPRs (row = gate*1024 + slice*16 + (lane&15)).
__global__ __launch_bounds__(512, 2) void lstm_recur_k(
    const float* __restrict__ Whh_f, const float* __restrict__ Whh_r,
    const float* __restrict__ h0, const float* __restrict__ c0,
    const float* __restrict__ X,   // [2048][8192]
    float* h_buf,                  // [2 dir][2 buf][1024]
    int* flags,                    // [2 dir][64]
    float* __restrict__ hs_out)    // [2048][2048]
{
    const int bid = blockIdx.x;
    const int dir = bid & 1;
    const int slice = bid >> 1;
    const int tid = threadIdx.x;
    const int lane = tid & 63;
    const int wave = tid >> 6;

    __shared__ float h_lds[1024];
    __shared__ float part[8 * 64];
    __shared__ float gv[64];
    __shared__ float c_st[16];

    const float* Whh = dir ? Whh_r : Whh_f;
    float* hb = h_buf + dir * 2048;
    int* fl = flags + dir * 64;

    const int gate = lane >> 4, kk = lane & 15;
    const int row = gate * HDIM + slice * 16 + kk;  // 0..4095
    const int coff = wave * 128;

    // weights -> registers (one-time)
    float w[128];
    {
        const float4* wp = (const float4*)(Whh + (size_t)row * HDIM + coff);
#pragma unroll
        for (int i = 0; i < 32; ++i) {
            float4 v = wp[i];
            w[4 * i + 0] = v.x; w[4 * i + 1] = v.y; w[4 * i + 2] = v.z; w[4 * i + 3] = v.w;
        }
    }
    // init h0/c0 slices, then release own flag = 0
    if (tid < 16) {
        float hv = h0[dir * HDIM + slice * 16 + tid];
        __hip_atomic_store(&hb[slice * 16 + tid], hv, __ATOMIC_RELAXED, __HIP_MEMORY_SCOPE_AGENT);
        c_st[tid] = c0[dir * HDIM + slice * 16 + tid];
    }
    if (tid == 0) __hip_atomic_store(&fl[slice], 0, __ATOMIC_RELEASE, __HIP_MEMORY_SCOPE_AGENT);

    for (int t = 0; t < TT; ++t) {
        // wait until every producer slice has published h_t
        if (tid < 64) {
            while (__hip_atomic_load(&fl[tid], __ATOMIC_ACQUIRE, __HIP_MEMORY_SCOPE_AGENT) < t) {
                __builtin_amdgcn_s_sleep(2);
            }
        }
        __syncthreads();
        // stage h_t -> LDS
        const float* hsrc = hb + (t & 1) * 1024;
        h_lds[tid]       = __hip_atomic_load(&hsrc[tid],       __ATOMIC_RELAXED, __HIP_MEMORY_SCOPE_AGENT);
        h_lds[tid + 512] = __hip_atomic_load(&hsrc[tid + 512], __ATOMIC_RELAXED, __HIP_MEMORY_SCOPE_AGENT);
        __syncthreads();
        // partial GEMV: this lane's row over its 128-col chunk
        float a0 = 0.f, a1 = 0.f;
        const float4* h4 = (const float4*)(h_lds + coff);
#pragma unroll
        for (int i = 0; i < 32; i += 2) {
            float4 x = h4[i], y = h4[i + 1];
            a0 = fmaf(w[4 * i + 0], x.x, a0); a0 = fmaf(w[4 * i + 1], x.y, a0);
            a0 = fmaf(w[4 * i + 2], x.z, a0); a0 = fmaf(w[4 * i + 3], x.w, a0);
            a1 = fmaf(w[4 * i + 4], y.x, a1); a1 = fmaf(w[4 * i + 5], y.y, a1);
            a1 = fmaf(w[4 * i + 6], y.z, a1); a1 = fmaf(w[4 * i + 7], y.w, a1);
        }
        part[wave * 64 + lane] = a0 + a1;
        __syncthreads();
        // reduce 8 col-chunks + add precomputed x-projection
        if (tid < 64) {
            float g = 0.f;
#pragma unroll
            for (int wv = 0; wv < 8; ++wv) g += part[wv * 64 + tid];
            int tx = dir ? (TT - 1 - t) : t;
            g += X[(size_t)tx * (2 * G4) + dir * G4 + row];
            gv[tid] = g;
        }
        __syncthreads();
        // gate math + publish h_{t+1}
        if (tid < 16) {
            float iv = sigm(gv[tid]);
            float fv = sigm(gv[16 + tid]);
            float gg = tanh_fast(gv[32 + tid]);
            float ov = sigm(gv[48 + tid]);
            float c = fv * c_st[tid] + iv * gg;
            c_st[tid] = c;
            float h = ov * tanh_fast(c);
            int tx = dir ? (TT - 1 - t) : t;
            hs_out[(size_t)tx * 2048 + dir * HDIM + slice * 16 + tid] = h;
            __hip_atomic_store(&hb[((t + 1) & 1) * 1024 + slice * 16 + tid], h,
                               __ATOMIC_RELAXED, __HIP_MEMORY_SCOPE_AGENT);
        }
        if (tid == 0) __hip_atomic_store(&fl[slice], t + 1, __ATOMIC_RELEASE, __HIP_MEMORY_SCOPE_AGENT);
    }
}

// ---------------- feats = lstm_out @ W_tag^T + b_tag ----------------
__global__ __launch_bounds__(256) void feats_k(const float* __restrict__ hs,
                                               const float* __restrict__ Wtag,
                                               const float* __restrict__ btag,
                                               float* __restrict__ feats) {
    const int t = blockIdx.x;
    const int lane = threadIdx.x & 63, wave = threadIdx.x >> 6;
    const float* ht = hs + (size_t)t * 2048;
    for (int j = wave; j < KTAG; j += 4) {
        const float* wr = Wtag + (size_t)j * 2048;
        float acc = 0.f;
#pragma unroll
        for (int i = 0; i < 32; ++i) acc += wr[i * 64 + lane] * ht[i * 64 + lane];
#pragma unroll
        for (int off = 32; off; off >>= 1) acc += __shfl_xor(acc, off);
        if (lane == 0) feats[t * KTAG + j] = acc + btag[j];
    }
}

// ---------------- Viterbi (single wave) ----------------
__global__ __launch_bounds__(64) void viterbi_k(const float* __restrict__ feats,
                                                const float* __restrict__ trans,
                                                float* __restrict__ out) {
    __shared__ float fv[KTAG];
    __shared__ unsigned char bps[TT * KTAG];
    __shared__ short path[TT];
    __shared__ float term[KTAG];
    const int j = threadIdx.x;
    float tr[KTAG];
    float tEnd = 0.f;
    if (j < KTAG) {
#pragma unroll
        for (int p = 0; p < KTAG; ++p) tr[p] = trans[j * KTAG + p];
        tEnd = trans[END_TAG * KTAG + j];
        fv[j] = (j == START_TAG) ? 0.0f : NEGV;
    }
    __syncthreads();
    for (int t = 0; t < TT; ++t) {
        float m = -3.4e38f;
        int bp = 0;
        float ft = 0.f;
        if (j < KTAG) {
            ft = feats[t * KTAG + j];
#pragma unroll
            for (int p = 0; p < KTAG; ++p) {
                float v = tr[p] + fv[p];
                if (v > m) { m = v; bp = p; }
            }
        }
        __syncthreads();
        if (j < KTAG) {
            fv[j] = m + ft;
            bps[t * KTAG + j] = (unsigned char)bp;
        }
        __syncthreads();
    }
    if (j < KTAG) term[j] = fv[j] + tEnd;
    __syncthreads();
    if (j == 0) {
        float best = term[0];
        int bt = 0;
        for (int p = 1; p < KTAG; ++p)
            if (term[p] > best) { best = term[p]; bt = p; }
        out[0] = best;
        int tag = bt;
        for (int t = TT - 1; t >= 0; --t) {
            path[t] = (short)tag;
            tag = bps[t * KTAG + tag];
        }
    }
    __syncthreads();
    for (int t = threadIdx.x; t < TT; t += 64) out[1 + t] = (float)path[t];
}

// ---------------- host ----------------
extern "C" void kernel_launch(void* const* d_in, const int* in_sizes, int n_in,
                              void* d_out, int out_size, void* d_ws, size_t ws_size,
                              hipStream_t stream) {
    const float* seq   = (const float*)d_in[0];
    const float* h0    = (const float*)d_in[1];
    const float* c0    = (const float*)d_in[2];
    const float* Wih_f = (const float*)d_in[3];
    const float* Whh_f = (const float*)d_in[4];
    const float* bih_f = (const float*)d_in[5];
    const float* bhh_f = (const float*)d_in[6];
    const float* Wih_r = (const float*)d_in[7];
    const float* Whh_r = (const float*)d_in[8];
    const float* bih_r = (const float*)d_in[9];
    const float* bhh_r = (const float*)d_in[10];
    const float* Wtag  = (const float*)d_in[11];
    const float* btag  = (const float*)d_in[12];
    const float* trans = (const float*)d_in[13];

    char* ws = (char*)d_ws;
    const size_t MB = 1ull << 20;
    __hip_bfloat16* seq_bf = (__hip_bfloat16*)(ws);              // 8 MB
    __hip_bfloat16* w_bf   = (__hip_bfloat16*)(ws + 8 * MB);     // 32 MB
    float* bias  = (float*)(ws + 40 * MB);                       // 32 KB
    float* X     = (float*)(ws + 41 * MB);                       // 64 MB
    float* hs    = (float*)(ws + 105 * MB);                      // 16 MB
    float* feats = (float*)(ws + 121 * MB);                      // 192 KB
    float* h_buf = (float*)(ws + 122 * MB);                      // 16 KB
    int*   flags = (int*)(ws + 122 * MB + 16384);                // 512 B

    hipMemsetAsync(flags, 0xFF, 2 * 64 * sizeof(int), stream);
    convert_bf16_k<<<256, 256, 0, stream>>>(seq, seq_bf, DD * TT);
    convert_bf16_k<<<512, 256, 0, stream>>>(Wih_f, w_bf, G4 * DD);
    convert_bf16_k<<<512, 256, 0, stream>>>(Wih_r, w_bf + (size_t)G4 * DD, G4 * DD);
    make_bias_k<<<32, 256, 0, stream>>>(bih_f, bhh_f, bih_r, bhh_r, bias);
    gemm_x_k<<<dim3(64, 16), 256, 0, stream>>>(seq_bf, w_bf, bias, X);

    {
        const float* a0 = Whh_f; const float* a1 = Whh_r;
        const float* a2 = h0;    const float* a3 = c0;
        const float* a4 = X;     float* a5 = h_buf;
        int* a6 = flags;         float* a7 = hs;
        void* args[] = {&a0, &a1, &a2, &a3, &a4, &a5, &a6, &a7};
        hipLaunchCooperativeKernel((const void*)lstm_recur_k, dim3(128), dim3(512), args, 0, stream);
    }

    feats_k<<<TT, 256, 0, stream>>>(hs, Wtag, btag, feats);
    viterbi_k<<<1, 64, 0, stream>>>(feats, trans, (float*)d_out);
}